// Round 20
// baseline (161.506 us; speedup 1.0000x reference)
//
#include <hip/hip_runtime.h>
#include <hip/hip_bf16.h>

#define BATCH 4
#define S_LEN 2048
#define D_DIM 1024
#define NHEAD 16
#define HDIM 64

// Q pre-scale: 1/sqrt(HDIM) * log2(e), so softmax works in exp2 domain.
#define QSCALE 0.18033688011112042f

typedef __attribute__((ext_vector_type(8))) __bf16 bf16x8;
typedef __attribute__((ext_vector_type(4))) __bf16 bf16x4;
typedef __attribute__((ext_vector_type(4))) float f32x4;
typedef __attribute__((ext_vector_type(16))) float f32x16;

static __device__ inline unsigned int bf16_bits(float f) {
    __bf16 h = (__bf16)f;
    return (unsigned int)__builtin_bit_cast(unsigned short, h);
}
static __device__ inline unsigned int pkbf(float a, float b) {
    return bf16_bits(a) | (bf16_bits(b) << 16);
}

// ---------------------------------------------------------------------------
// Fused fp32 -> bf16 convert for x and the three W matrices (one launch).
// ---------------------------------------------------------------------------
#define NX8 1048576   // x: 8.39M elems / 8
#define NW8 131072    // each W: 1.05M elems / 8 (= 2^17)

__global__ __launch_bounds__(256) void cvt_all_kernel(
    const float* __restrict__ x,  const float* __restrict__ Wq,
    const float* __restrict__ Wk, const float* __restrict__ Wv,
    __bf16* __restrict__ xb, __bf16* __restrict__ wcat)
{
    const int i = blockIdx.x * 256 + threadIdx.x;
    const float* src;
    __bf16* dst;
    if (i < NX8) {
        src = x + (size_t)i * 8;
        dst = xb + (size_t)i * 8;
    } else {
        const int i2 = i - NX8;              // 0 .. 3*NW8-1
        const int w  = i2 >> 17;             // 0..2
        src = ((w == 0) ? Wq : (w == 1) ? Wk : Wv) + (size_t)(i2 & (NW8 - 1)) * 8;
        dst = wcat + (size_t)i2 * 8;
    }
    const f32x4* p = reinterpret_cast<const f32x4*>(src);
    f32x4 a = p[0], b = p[1];
    bf16x8 r;
    r[0] = (__bf16)a[0]; r[1] = (__bf16)a[1]; r[2] = (__bf16)a[2]; r[3] = (__bf16)a[3];
    r[4] = (__bf16)b[0]; r[5] = (__bf16)b[1]; r[6] = (__bf16)b[2]; r[7] = (__bf16)b[3];
    *reinterpret_cast<bf16x8*>(dst) = r;
}

// ---------------------------------------------------------------------------
// Projection GEMM (m97-style): C[m][n] = sum_d xb[m][d] * wb[n][d]
// q output is pre-scaled by QSCALE. q,k -> [bh][s][e]; v -> [bh][e][s].
// ---------------------------------------------------------------------------
__global__ __launch_bounds__(256) void proj_gemm_kernel(
    const __bf16* __restrict__ xb, const __bf16* __restrict__ wb,
    __bf16* __restrict__ qo, __bf16* __restrict__ ko, __bf16* __restrict__ vto)
{
    __shared__ __bf16 As[128][32];
    __shared__ __bf16 Bs[128][32];

    const int tid = threadIdx.x;
    const int l  = tid & 63;
    const int w  = tid >> 6;
    const int wm = w >> 1, wn = w & 1;
    const int lr = l & 15, lg = l >> 4, lk = lg * 8;
    const int m0 = blockIdx.y * 128;
    const int n0 = blockIdx.x * 128;
    const int mat = n0 >> 10;           // 0=q,1=k,2=v
    const int nb  = n0 & 1023;

    const int sr = l >> 2;
    const int sc = (l & 3) * 8;
    const int g0 = w * 2;

    f32x4 acc[4][4] = {};

    for (int d = 0; d < D_DIM; d += 32) {
        __builtin_amdgcn_global_load_lds(
            (const __attribute__((address_space(1))) void*)(xb + (size_t)(m0 + g0 * 16 + sr) * D_DIM + d + sc),
            (__attribute__((address_space(3))) void*)(&As[g0 * 16][0]), 16, 0, 0);
        __builtin_amdgcn_global_load_lds(
            (const __attribute__((address_space(1))) void*)(xb + (size_t)(m0 + (g0 + 1) * 16 + sr) * D_DIM + d + sc),
            (__attribute__((address_space(3))) void*)(&As[(g0 + 1) * 16][0]), 16, 0, 0);
        __builtin_amdgcn_global_load_lds(
            (const __attribute__((address_space(1))) void*)(wb + (size_t)(n0 + g0 * 16 + sr) * D_DIM + d + sc),
            (__attribute__((address_space(3))) void*)(&Bs[g0 * 16][0]), 16, 0, 0);
        __builtin_amdgcn_global_load_lds(
            (const __attribute__((address_space(1))) void*)(wb + (size_t)(n0 + (g0 + 1) * 16 + sr) * D_DIM + d + sc),
            (__attribute__((address_space(3))) void*)(&Bs[(g0 + 1) * 16][0]), 16, 0, 0);
        __syncthreads();

        bf16x8 af[4], bfr[4];
        #pragma unroll
        for (int mi = 0; mi < 4; ++mi)
            af[mi] = *reinterpret_cast<const bf16x8*>(&As[wm * 64 + mi * 16 + lr][lk]);
        #pragma unroll
        for (int ni = 0; ni < 4; ++ni)
            bfr[ni] = *reinterpret_cast<const bf16x8*>(&Bs[wn * 64 + ni * 16 + lr][lk]);
        #pragma unroll
        for (int mi = 0; mi < 4; ++mi) {
            #pragma unroll
            for (int ni = 0; ni < 4; ++ni)
                acc[mi][ni] = __builtin_amdgcn_mfma_f32_16x16x32_bf16(
                    af[mi], bfr[ni], acc[mi][ni], 0, 0, 0);
        }
        __syncthreads();
    }

    const float oscale = (mat == 0) ? QSCALE : 1.0f;
    #pragma unroll
    for (int mi = 0; mi < 4; ++mi) {
        const int mrow = m0 + wm * 64 + mi * 16 + lg * 4;
        const int b = mrow >> 11;
        const int s = mrow & (S_LEN - 1);
        #pragma unroll
        for (int ni = 0; ni < 4; ++ni) {
            const int n = nb + wn * 64 + ni * 16 + lr;
            const int h = n >> 6;
            const int e = n & 63;
            if (mat == 2) {
                bf16x4 pk;
                #pragma unroll
                for (int r = 0; r < 4; ++r) pk[r] = (__bf16)acc[mi][ni][r];
                *reinterpret_cast<bf16x4*>(
                    vto + ((size_t)(b * NHEAD + h) * HDIM + e) * S_LEN + s) = pk;
            } else {
                __bf16* __restrict__ dst = (mat == 0) ? qo : ko;
                #pragma unroll
                for (int r = 0; r < 4; ++r)
                    dst[((size_t)(b * NHEAD + h) * S_LEN + (s + r)) * HDIM + e] =
                        (__bf16)(acc[mi][ni][r] * oscale);
            }
        }
    }
}

// ---------------------------------------------------------------------------
// Coalesced staging of a 64x64 bf16 tile (8KB) into linear LDS with
// XOR-pre-swizzled SOURCE (rule #21: linear dest + inverse-swz source +
// swz read). LDS[row][c] = src[row][c ^ (row&7)] (chunks of 8 elems).
// src_base must point at the tile origin (row 0, col 0); row_stride in
// elems. Per inst: lane l -> row i*8+(l>>3), LDS chunk l&7, src chunk
// (l&7)^(l>>3). Source reads stay within the 128B tile row -> 100% line
// utilization.
// NOTE (R19 bug): K's kv offset is a ROW offset -- callers pre-offset the
// base pointer; col0 is only for V (kv really is a column there).
// ---------------------------------------------------------------------------
__device__ __attribute__((always_inline)) inline void stage_tile(
    __bf16* dst, const __bf16* __restrict__ src_base, size_t row_stride,
    int col0, int l)
{
    const int r8   = l >> 3;                   // row within 8-row group
    const int csw  = ((l & 7) ^ r8) * 8;       // swizzled source col (elems)
    #pragma unroll
    for (int i = 0; i < 8; ++i) {
        __builtin_amdgcn_global_load_lds(
            (const __attribute__((address_space(1))) void*)(
                src_base + (size_t)(i * 8 + r8) * row_stride + col0 + csw),
            (__attribute__((address_space(3))) void*)(dst + i * 512),
            16, 0, 0);
    }
}

// ---------------------------------------------------------------------------
// Softmax + pack for one 32-row tile T (static index). Consumes s0/s1
// (scores for kv blocks 0/1), updates m/l/acc[T], emits 4 PV B-frags.
// ---------------------------------------------------------------------------
template<int T, bool MASK>
__device__ __attribute__((always_inline)) inline void sm_pack(
    int kv0, int qbase, int lq, int lh,
    f32x16& s0, f32x16& s1,
    float (&m_acc)[2], float (&l_lane)[2], f32x16 (&acc)[2][2],
    bf16x8 (&pB)[4])
{
    if (MASK) {
        const int qrow = qbase + T * 32 + lq;
        #pragma unroll
        for (int r = 0; r < 16; ++r) {
            const int kvl = (r & 3) + 8 * (r >> 2) + 4 * lh;
            if (kv0 + kvl > qrow)      s0[r] = -1e30f;
            if (kv0 + 32 + kvl > qrow) s1[r] = -1e30f;
        }
    }

    float tm[8];
    #pragma unroll
    for (int r = 0; r < 8; ++r)
        tm[r] = fmaxf(fmaxf(s0[r], s0[r + 8]), fmaxf(s1[r], s1[r + 8]));
    float mx = fmaxf(fmaxf(fmaxf(tm[0], tm[1]), fmaxf(tm[2], tm[3])),
                     fmaxf(fmaxf(tm[4], tm[5]), fmaxf(tm[6], tm[7])));

    if (!__all(mx - m_acc[T] <= 8.0f)) {
        mx = fmaxf(mx, __shfl_xor(mx, 32));
        const float mnew = fmaxf(m_acc[T], mx);
        const float sc = exp2f(m_acc[T] - mnew);
        l_lane[T] *= sc;
        acc[T][0] *= sc;
        acc[T][1] *= sc;
        m_acc[T] = mnew;
    }

    const float mt = m_acc[T];
    float p0[16], p1[16];
    float psum = 0.0f;
    #pragma unroll
    for (int r = 0; r < 16; ++r) { p0[r] = exp2f(s0[r] - mt); psum += p0[r]; }
    #pragma unroll
    for (int r = 0; r < 16; ++r) { p1[r] = exp2f(s1[r] - mt); psum += p1[r]; }
    l_lane[T] += psum;

    #pragma unroll
    for (int sl = 0; sl < 2; ++sl) {
        const int b = sl * 8;
        {
            unsigned A = pkbf(p0[b + 0], p0[b + 1]);
            unsigned C = pkbf(p0[b + 2], p0[b + 3]);
            unsigned B = pkbf(p0[b + 4], p0[b + 5]);
            unsigned D = pkbf(p0[b + 6], p0[b + 7]);
            auto r0 = __builtin_amdgcn_permlane32_swap((int)A, (int)B, false, false);
            auto r1 = __builtin_amdgcn_permlane32_swap((int)C, (int)D, false, false);
            uint4 u;
            u.x = (unsigned)r0[0]; u.y = (unsigned)r1[0];
            u.z = (unsigned)r0[1]; u.w = (unsigned)r1[1];
            pB[sl] = __builtin_bit_cast(bf16x8, u);
        }
        {
            unsigned A = pkbf(p1[b + 0], p1[b + 1]);
            unsigned C = pkbf(p1[b + 2], p1[b + 3]);
            unsigned B = pkbf(p1[b + 4], p1[b + 5]);
            unsigned D = pkbf(p1[b + 6], p1[b + 7]);
            auto r0 = __builtin_amdgcn_permlane32_swap((int)A, (int)B, false, false);
            auto r1 = __builtin_amdgcn_permlane32_swap((int)C, (int)D, false, false);
            uint4 u;
            u.x = (unsigned)r0[0]; u.y = (unsigned)r1[0];
            u.z = (unsigned)r0[1]; u.w = (unsigned)r1[1];
            pB[2 + sl] = __builtin_bit_cast(bf16x8, u);
        }
    }
}

// ---------------------------------------------------------------------------
// 32x32 MFMA attention iteration, K/V from swizzled LDS tiles.
// T15 double-pipeline retained. Fragment read: row = sub*32+lq, logical
// chunk = ks*2+lh, LDS chunk = logical ^ (row&7).
// ---------------------------------------------------------------------------
template<bool MASK>
__device__ __attribute__((always_inline)) inline void pair_compute(
    int kv0, int qbase, int lq, int lh,
    const __bf16* __restrict__ kt, const __bf16* __restrict__ vt,
    const bf16x8 (&qB)[2][4],
    float (&m_acc)[2], float (&l_lane)[2], f32x16 (&acc)[2][2])
{
    // ---- K A-frags from LDS ----
    bf16x8 kA[2][4];
    #pragma unroll
    for (int kvb = 0; kvb < 2; ++kvb) {
        const int row = kvb * 32 + lq;
        const int sw  = row & 7;
        #pragma unroll
        for (int ks = 0; ks < 4; ++ks)
            kA[kvb][ks] = *reinterpret_cast<const bf16x8*>(
                kt + row * 64 + ((ks * 2 + lh) ^ sw) * 8);
    }

    // ---- QK^T both tiles, issued back-to-back ----
    f32x16 s00 = {}, s01 = {}, s10 = {}, s11 = {};
    __builtin_amdgcn_s_setprio(1);
    #pragma unroll
    for (int ks = 0; ks < 4; ++ks)
        s00 = __builtin_amdgcn_mfma_f32_32x32x16_bf16(kA[0][ks], qB[0][ks], s00, 0, 0, 0);
    #pragma unroll
    for (int ks = 0; ks < 4; ++ks)
        s01 = __builtin_amdgcn_mfma_f32_32x32x16_bf16(kA[1][ks], qB[0][ks], s01, 0, 0, 0);
    #pragma unroll
    for (int ks = 0; ks < 4; ++ks)
        s10 = __builtin_amdgcn_mfma_f32_32x32x16_bf16(kA[0][ks], qB[1][ks], s10, 0, 0, 0);
    #pragma unroll
    for (int ks = 0; ks < 4; ++ks)
        s11 = __builtin_amdgcn_mfma_f32_32x32x16_bf16(kA[1][ks], qB[1][ks], s11, 0, 0, 0);
    __builtin_amdgcn_s_setprio(0);

    // ---- V A-frags from LDS (read now; hides under SM(t0)) ----
    bf16x8 vA[2][4];
    #pragma unroll
    for (int eb = 0; eb < 2; ++eb) {
        const int row = eb * 32 + lq;
        const int sw  = row & 7;
        #pragma unroll
        for (int ks = 0; ks < 4; ++ks)
            vA[eb][ks] = *reinterpret_cast<const bf16x8*>(
                vt + row * 64 + ((ks * 2 + lh) ^ sw) * 8);
    }

    // ---- SM(t0) ----
    bf16x8 pB0[4];
    sm_pack<0, MASK>(kv0, qbase, lq, lh, s00, s01, m_acc, l_lane, acc, pB0);

    // ---- PV(t0) before SM(t1): matrix pipe covers SM1 VALU ----
    __builtin_amdgcn_s_setprio(1);
    #pragma unroll
    for (int eb = 0; eb < 2; ++eb)
        #pragma unroll
        for (int ks = 0; ks < 4; ++ks)
            acc[0][eb] = __builtin_amdgcn_mfma_f32_32x32x16_bf16(
                vA[eb][ks], pB0[ks], acc[0][eb], 0, 0, 0);
    __builtin_amdgcn_s_setprio(0);

    // ---- SM(t1) ----
    bf16x8 pB1[4];
    sm_pack<1, MASK>(kv0, qbase, lq, lh, s10, s11, m_acc, l_lane, acc, pB1);

    // ---- PV(t1) ----
    __builtin_amdgcn_s_setprio(1);
    #pragma unroll
    for (int eb = 0; eb < 2; ++eb)
        #pragma unroll
        for (int ks = 0; ks < 4; ++ks)
            acc[1][eb] = __builtin_amdgcn_mfma_f32_32x32x16_bf16(
                vA[eb][ks], pB1[ks], acc[1][eb], 0, 0, 0);
    __builtin_amdgcn_s_setprio(0);
}

// ---------------------------------------------------------------------------
// Split-K merge helpers (static register indexing only, rule #20).
// Merge region: per wave, lane l owns floats [l*35 .. l*35+33]:
//   [0]=m, [1]=row-sum l, [2..33]=acc. Stride 35 -> conflict-free.
// ---------------------------------------------------------------------------
template<int T>
__device__ __attribute__((always_inline)) inline void expose_tile(
    float* region, int l, const float (&m_acc)[2], const float (&lt)[2],
    const f32x16 (&acc)[2][2])
{
    float* p = region + l * 35;
    p[0] = m_acc[T];
    p[1] = lt[T];
    #pragma unroll
    for (int eb = 0; eb < 2; ++eb)
        #pragma unroll
        for (int r = 0; r < 16; ++r)
            p[2 + eb * 16 + r] = acc[T][eb][r];
}

template<int T>
__device__ __attribute__((always_inline)) inline void merge_out(
    const float* region, int l, int lh, const float (&m_acc)[2],
    const float (&lt)[2], const f32x16 (&acc)[2][2], float* orow)
{
    const float* p = region + l * 35;
    const float mo = p[0];
    const float lo = p[1];
    const float mn = fmaxf(m_acc[T], mo);
    const float s_own = exp2f(m_acc[T] - mn);
    const float s_oth = exp2f(mo - mn);
    const float liv = 1.0f / (lt[T] * s_own + lo * s_oth);
    #pragma unroll
    for (int eb = 0; eb < 2; ++eb) {
        #pragma unroll
        for (int g = 0; g < 4; ++g) {
            f32x4 ox;
            #pragma unroll
            for (int r = 0; r < 4; ++r) {
                const float oth = p[2 + eb * 16 + g * 4 + r];
                ox[r] = (acc[T][eb][g * 4 + r] * s_own + oth * s_oth) * liv;
            }
            *reinterpret_cast<f32x4*>(orow + eb * 32 + g * 8 + 4 * lh) = ox;
        }
    }
}

// ---------------------------------------------------------------------------
// Causal flash attention, SPLIT-K + cooperative coalesced LDS staging:
// 2-wave block owns chunk pair (tp, 31-tp) (uniform 33 kv-blocks). Per
// super-iter: wave0 stages K tiles (j, j+1), wave1 stages V tiles -> barrier
// -> wave w computes kv-block j+w from LDS -> barrier. Scattered per-lane
// global loads (32-64 lines/inst) replaced by coalesced staging (~4x fewer
// L1/TCP requests). Merge reuses staging LDS after final barrier.
// ---------------------------------------------------------------------------
__global__ __launch_bounds__(128, 2) void attn_kernel(
    const __bf16* __restrict__ q, const __bf16* __restrict__ k,
    const __bf16* __restrict__ vt, float* __restrict__ out)
{
    __shared__ __align__(16) unsigned char smem[32768];   // K2/V2 tiles | merge

    const int tid = threadIdx.x;
    const int l  = tid & 63;
    const int w  = tid >> 6;             // 0/1: kv parity
    const int lq = l & 31;
    const int lh = l >> 5;

    const int n   = blockIdx.x;          // 0..1023
    const int xcd = n & 7;
    const int m   = n >> 3;              // 0..127
    const int tp  = m >> 3;              // 0..15: chunk pair (tp, 31-tp)
    const int bh  = xcd * 8 + (m & 7);

    const __bf16* __restrict__ kp = k  + (size_t)bh * S_LEN * HDIM;
    const __bf16* __restrict__ vp = vt + (size_t)bh * HDIM * S_LEN;
    const int bq = bh >> 4;
    const int hq = bh & 15;

    __bf16* klds0 = reinterpret_cast<__bf16*>(smem);            // 8KB
    __bf16* klds1 = klds0 + 4096;                               // 8KB
    __bf16* vlds0 = klds1 + 4096;                               // 8KB
    __bf16* vlds1 = vlds0 + 4096;                               // 8KB

    #pragma unroll 1
    for (int ph = 0; ph < 2; ++ph) {
        const int qq    = ph ? (31 - tp) : tp;   // 64-row chunk index
        const int qbase = qq * 64;
        const int nkv   = qq + 1;

        // Q B-frags: col = own q-row, k = e (4 slabs of 16)
        const int kcol = 8 * lh;
        const __bf16* __restrict__ qp = q + ((size_t)bh * S_LEN + qbase) * HDIM;
        bf16x8 qB[2][4];
        #pragma unroll
        for (int t = 0; t < 2; ++t)
            #pragma unroll
            for (int ks = 0; ks < 4; ++ks)
                qB[t][ks] = *reinterpret_cast<const bf16x8*>(
                    qp + (size_t)(t * 32 + lq) * HDIM + ks * 16 + kcol);

        float m_acc[2], l_lane[2];
        f32x16 acc[2][2] = {};
        #pragma unroll
        for (int t = 0; t < 2; ++t) { m_acc[t] = -1e30f; l_lane[t] = 0.0f; }

        const int ns = (nkv + 1) >> 1;       // super-iterations
        #pragma unroll 1
        for (int s = 0; s < ns; ++s) {
            const int j0 = 2 * s;
            const int j1 = 2 * s + 1;
            // ---- cooperative staging: wave0 K (kv = ROW offset -> pre-offset
            //      base), wave1 V (kv = column offset) ----
            if (w == 0) {
                stage_tile(klds0, kp + (size_t)j0 * 64 * HDIM, HDIM, 0, l);
                if (j1 < nkv) stage_tile(klds1, kp + (size_t)j1 * 64 * HDIM, HDIM, 0, l);
            } else {
                stage_tile(vlds0, vp, S_LEN, j0 * 64, l);
                if (j1 < nkv) stage_tile(vlds1, vp, S_LEN, j1 * 64, l);
            }
            __syncthreads();                 // drains vmcnt (compiler)

            const int j = j0 + w;
            if (j < nkv) {
                const __bf16* kt = (w == 0) ? klds0 : klds1;
                const __bf16* vl = (w == 0) ? vlds0 : vlds1;
                if (j == nkv - 1)
                    pair_compute<true>(j * 64, qbase, lq, lh, kt, vl,
                                       qB, m_acc, l_lane, acc);
                else
                    pair_compute<false>(j * 64, qbase, lq, lh, kt, vl,
                                        qB, m_acc, l_lane, acc);
            }
            __syncthreads();                 // tiles reusable next super-iter
        }

        // ---- wave-local row sums of l (row = lanes l and l^32) ----
        float lt[2];
        lt[0] = l_lane[0] + __shfl_xor(l_lane[0], 32);
        lt[1] = l_lane[1] + __shfl_xor(l_lane[1], 32);

        // ---- merge via LDS (reuses staging buffer) ----
        float* mbase = reinterpret_cast<float*>(smem);
        float* myreg = mbase + w * (64 * 35);
        if (w == 0) expose_tile<1>(myreg, l, m_acc, lt, acc);
        else        expose_tile<0>(myreg, l, m_acc, lt, acc);
        __syncthreads();

        const float* other = mbase + (1 - w) * (64 * 35);
        if (w == 0) {
            float* orow = out + (size_t)(bq * S_LEN + qbase + 0 * 32 + lq) * D_DIM + hq * HDIM;
            merge_out<0>(other, l, lh, m_acc, lt, acc, orow);
        } else {
            float* orow = out + (size_t)(bq * S_LEN + qbase + 1 * 32 + lq) * D_DIM + hq * HDIM;
            merge_out<1>(other, l, lh, m_acc, lt, acc, orow);
        }
        __syncthreads();   // LDS reused by next phase
    }
}

extern "C" void kernel_launch(void* const* d_in, const int* in_sizes, int n_in,
                              void* d_out, int out_size, void* d_ws, size_t ws_size,
                              hipStream_t stream)
{
    const float* x  = (const float*)d_in[0];
    const float* Wq = (const float*)d_in[1];
    const float* Wk = (const float*)d_in[2];
    const float* Wv = (const float*)d_in[3];
    float* out = (float*)d_out;

    const size_t x_elems = (size_t)BATCH * S_LEN * D_DIM;
    __bf16* xb   = (__bf16*)d_out;          // scratch in d_out (overwritten)
    __bf16* wcat = xb + x_elems;

    const size_t per_buf = (size_t)BATCH * NHEAD * S_LEN * HDIM;
    __bf16* qb = (__bf16*)d_ws;
    __bf16* kb = qb + per_buf;
    __bf16* vb = kb + per_buf;

    cvt_all_kernel<<<dim3((NX8 + 3 * NW8) / 256), dim3(256), 0, stream>>>(
        x, Wq, Wk, Wv, xb, wcat);

    dim3 grid1(3 * D_DIM / 128, (BATCH * S_LEN) / 128);   // (24, 64)
    proj_gemm_kernel<<<grid1, dim3(256), 0, stream>>>(xb, wcat, qb, kb, vb);

    attn_kernel<<<dim3(1024), dim3(128), 0, stream>>>(qb, kb, vb, out);
}

// Round 21
// 156.487 us; speedup vs baseline: 1.0321x; 1.0321x over previous
//
#include <hip/hip_runtime.h>
#include <hip/hip_bf16.h>

#define BATCH 4
#define S_LEN 2048
#define D_DIM 1024
#define NHEAD 16
#define HDIM 64

// Q pre-scale: 1/sqrt(HDIM) * log2(e), so softmax works in exp2 domain.
#define QSCALE 0.18033688011112042f

typedef __attribute__((ext_vector_type(8))) __bf16 bf16x8;
typedef __attribute__((ext_vector_type(4))) __bf16 bf16x4;
typedef __attribute__((ext_vector_type(4))) float f32x4;
typedef __attribute__((ext_vector_type(16))) float f32x16;

static __device__ inline unsigned int bf16_bits(float f) {
    __bf16 h = (__bf16)f;
    return (unsigned int)__builtin_bit_cast(unsigned short, h);
}
static __device__ inline unsigned int pkbf(float a, float b) {
    return bf16_bits(a) | (bf16_bits(b) << 16);
}

// ---------------------------------------------------------------------------
// Fused fp32 -> bf16 convert for x and the three W matrices (one launch).
// ---------------------------------------------------------------------------
#define NX8 1048576   // x: 8.39M elems / 8
#define NW8 131072    // each W: 1.05M elems / 8 (= 2^17)

__global__ __launch_bounds__(256) void cvt_all_kernel(
    const float* __restrict__ x,  const float* __restrict__ Wq,
    const float* __restrict__ Wk, const float* __restrict__ Wv,
    __bf16* __restrict__ xb, __bf16* __restrict__ wcat)
{
    const int i = blockIdx.x * 256 + threadIdx.x;
    const float* src;
    __bf16* dst;
    if (i < NX8) {
        src = x + (size_t)i * 8;
        dst = xb + (size_t)i * 8;
    } else {
        const int i2 = i - NX8;              // 0 .. 3*NW8-1
        const int w  = i2 >> 17;             // 0..2
        src = ((w == 0) ? Wq : (w == 1) ? Wk : Wv) + (size_t)(i2 & (NW8 - 1)) * 8;
        dst = wcat + (size_t)i2 * 8;
    }
    const f32x4* p = reinterpret_cast<const f32x4*>(src);
    f32x4 a = p[0], b = p[1];
    bf16x8 r;
    r[0] = (__bf16)a[0]; r[1] = (__bf16)a[1]; r[2] = (__bf16)a[2]; r[3] = (__bf16)a[3];
    r[4] = (__bf16)b[0]; r[5] = (__bf16)b[1]; r[6] = (__bf16)b[2]; r[7] = (__bf16)b[3];
    *reinterpret_cast<bf16x8*>(dst) = r;
}

// ---------------------------------------------------------------------------
// Projection GEMM (m97-style): C[m][n] = sum_d xb[m][d] * wb[n][d]
// q output is pre-scaled by QSCALE. q,k -> [bh][s][e]; v -> [bh][e][s].
// ---------------------------------------------------------------------------
__global__ __launch_bounds__(256) void proj_gemm_kernel(
    const __bf16* __restrict__ xb, const __bf16* __restrict__ wb,
    __bf16* __restrict__ qo, __bf16* __restrict__ ko, __bf16* __restrict__ vto)
{
    __shared__ __bf16 As[128][32];
    __shared__ __bf16 Bs[128][32];

    const int tid = threadIdx.x;
    const int l  = tid & 63;
    const int w  = tid >> 6;
    const int wm = w >> 1, wn = w & 1;
    const int lr = l & 15, lg = l >> 4, lk = lg * 8;
    const int m0 = blockIdx.y * 128;
    const int n0 = blockIdx.x * 128;
    const int mat = n0 >> 10;           // 0=q,1=k,2=v
    const int nb  = n0 & 1023;

    const int sr = l >> 2;
    const int sc = (l & 3) * 8;
    const int g0 = w * 2;

    f32x4 acc[4][4] = {};

    for (int d = 0; d < D_DIM; d += 32) {
        __builtin_amdgcn_global_load_lds(
            (const __attribute__((address_space(1))) void*)(xb + (size_t)(m0 + g0 * 16 + sr) * D_DIM + d + sc),
            (__attribute__((address_space(3))) void*)(&As[g0 * 16][0]), 16, 0, 0);
        __builtin_amdgcn_global_load_lds(
            (const __attribute__((address_space(1))) void*)(xb + (size_t)(m0 + (g0 + 1) * 16 + sr) * D_DIM + d + sc),
            (__attribute__((address_space(3))) void*)(&As[(g0 + 1) * 16][0]), 16, 0, 0);
        __builtin_amdgcn_global_load_lds(
            (const __attribute__((address_space(1))) void*)(wb + (size_t)(n0 + g0 * 16 + sr) * D_DIM + d + sc),
            (__attribute__((address_space(3))) void*)(&Bs[g0 * 16][0]), 16, 0, 0);
        __builtin_amdgcn_global_load_lds(
            (const __attribute__((address_space(1))) void*)(wb + (size_t)(n0 + (g0 + 1) * 16 + sr) * D_DIM + d + sc),
            (__attribute__((address_space(3))) void*)(&Bs[(g0 + 1) * 16][0]), 16, 0, 0);
        __syncthreads();

        bf16x8 af[4], bfr[4];
        #pragma unroll
        for (int mi = 0; mi < 4; ++mi)
            af[mi] = *reinterpret_cast<const bf16x8*>(&As[wm * 64 + mi * 16 + lr][lk]);
        #pragma unroll
        for (int ni = 0; ni < 4; ++ni)
            bfr[ni] = *reinterpret_cast<const bf16x8*>(&Bs[wn * 64 + ni * 16 + lr][lk]);
        #pragma unroll
        for (int mi = 0; mi < 4; ++mi) {
            #pragma unroll
            for (int ni = 0; ni < 4; ++ni)
                acc[mi][ni] = __builtin_amdgcn_mfma_f32_16x16x32_bf16(
                    af[mi], bfr[ni], acc[mi][ni], 0, 0, 0);
        }
        __syncthreads();
    }

    const float oscale = (mat == 0) ? QSCALE : 1.0f;
    #pragma unroll
    for (int mi = 0; mi < 4; ++mi) {
        const int mrow = m0 + wm * 64 + mi * 16 + lg * 4;
        const int b = mrow >> 11;
        const int s = mrow & (S_LEN - 1);
        #pragma unroll
        for (int ni = 0; ni < 4; ++ni) {
            const int n = nb + wn * 64 + ni * 16 + lr;
            const int h = n >> 6;
            const int e = n & 63;
            if (mat == 2) {
                bf16x4 pk;
                #pragma unroll
                for (int r = 0; r < 4; ++r) pk[r] = (__bf16)acc[mi][ni][r];
                *reinterpret_cast<bf16x4*>(
                    vto + ((size_t)(b * NHEAD + h) * HDIM + e) * S_LEN + s) = pk;
            } else {
                __bf16* __restrict__ dst = (mat == 0) ? qo : ko;
                #pragma unroll
                for (int r = 0; r < 4; ++r)
                    dst[((size_t)(b * NHEAD + h) * S_LEN + (s + r)) * HDIM + e] =
                        (__bf16)(acc[mi][ni][r] * oscale);
            }
        }
    }
}

// ---------------------------------------------------------------------------
// Softmax + pack for one 32-row tile T (static index). Consumes s0/s1
// (scores for kv blocks 0/1), updates m/l/acc[T], emits 4 PV B-frags.
// ---------------------------------------------------------------------------
template<int T, bool MASK>
__device__ __attribute__((always_inline)) inline void sm_pack(
    int kv0, int qbase, int lq, int lh,
    f32x16& s0, f32x16& s1,
    float (&m_acc)[2], float (&l_lane)[2], f32x16 (&acc)[2][2],
    bf16x8 (&pB)[4])
{
    if (MASK) {
        const int qrow = qbase + T * 32 + lq;
        #pragma unroll
        for (int r = 0; r < 16; ++r) {
            const int kvl = (r & 3) + 8 * (r >> 2) + 4 * lh;
            if (kv0 + kvl > qrow)      s0[r] = -1e30f;
            if (kv0 + 32 + kvl > qrow) s1[r] = -1e30f;
        }
    }

    float tm[8];
    #pragma unroll
    for (int r = 0; r < 8; ++r)
        tm[r] = fmaxf(fmaxf(s0[r], s0[r + 8]), fmaxf(s1[r], s1[r + 8]));
    float mx = fmaxf(fmaxf(fmaxf(tm[0], tm[1]), fmaxf(tm[2], tm[3])),
                     fmaxf(fmaxf(tm[4], tm[5]), fmaxf(tm[6], tm[7])));

    if (!__all(mx - m_acc[T] <= 8.0f)) {
        mx = fmaxf(mx, __shfl_xor(mx, 32));
        const float mnew = fmaxf(m_acc[T], mx);
        const float sc = exp2f(m_acc[T] - mnew);
        l_lane[T] *= sc;
        acc[T][0] *= sc;
        acc[T][1] *= sc;
        m_acc[T] = mnew;
    }

    const float mt = m_acc[T];
    float p0[16], p1[16];
    float psum = 0.0f;
    #pragma unroll
    for (int r = 0; r < 16; ++r) { p0[r] = exp2f(s0[r] - mt); psum += p0[r]; }
    #pragma unroll
    for (int r = 0; r < 16; ++r) { p1[r] = exp2f(s1[r] - mt); psum += p1[r]; }
    l_lane[T] += psum;

    #pragma unroll
    for (int sl = 0; sl < 2; ++sl) {
        const int b = sl * 8;
        {
            unsigned A = pkbf(p0[b + 0], p0[b + 1]);
            unsigned C = pkbf(p0[b + 2], p0[b + 3]);
            unsigned B = pkbf(p0[b + 4], p0[b + 5]);
            unsigned D = pkbf(p0[b + 6], p0[b + 7]);
            auto r0 = __builtin_amdgcn_permlane32_swap((int)A, (int)B, false, false);
            auto r1 = __builtin_amdgcn_permlane32_swap((int)C, (int)D, false, false);
            uint4 u;
            u.x = (unsigned)r0[0]; u.y = (unsigned)r1[0];
            u.z = (unsigned)r0[1]; u.w = (unsigned)r1[1];
            pB[sl] = __builtin_bit_cast(bf16x8, u);
        }
        {
            unsigned A = pkbf(p1[b + 0], p1[b + 1]);
            unsigned C = pkbf(p1[b + 2], p1[b + 3]);
            unsigned B = pkbf(p1[b + 4], p1[b + 5]);
            unsigned D = pkbf(p1[b + 6], p1[b + 7]);
            auto r0 = __builtin_amdgcn_permlane32_swap((int)A, (int)B, false, false);
            auto r1 = __builtin_amdgcn_permlane32_swap((int)C, (int)D, false, false);
            uint4 u;
            u.x = (unsigned)r0[0]; u.y = (unsigned)r1[0];
            u.z = (unsigned)r0[1]; u.w = (unsigned)r1[1];
            pB[2 + sl] = __builtin_bit_cast(bf16x8, u);
        }
    }
}

// ---------------------------------------------------------------------------
// 32x32 MFMA attention iteration, LDS-free, T15 double-pipeline:
// QK both tiles issued up front (SM(t0) VALU hides under QK(t1) MFMA exec);
// V loads issued before SM0 (L2 latency hidden under softmax);
// PV(t0) MFMAs issued BEFORE SM(t1) (PV0 matrix-pipe exec hides SM1 VALU).
// ---------------------------------------------------------------------------
template<bool MASK>
__device__ __attribute__((always_inline)) inline void pair_compute(
    int kv0, int qbase, int lq, int lh,
    const __bf16* __restrict__ kp, const __bf16* __restrict__ vp,
    const bf16x8 (&qB)[2][4],
    float (&m_acc)[2], float (&l_lane)[2], f32x16 (&acc)[2][2])
{
    const int kcol = 8 * lh;

    // ---- K A-frags (shared by both q-tiles) ----
    bf16x8 kA[2][4];
    #pragma unroll
    for (int kvb = 0; kvb < 2; ++kvb)
        #pragma unroll
        for (int ks = 0; ks < 4; ++ks)
            kA[kvb][ks] = *reinterpret_cast<const bf16x8*>(
                kp + (size_t)(kv0 + kvb * 32 + lq) * HDIM + ks * 16 + kcol);

    // ---- QK^T both tiles, issued back-to-back ----
    f32x16 s00 = {}, s01 = {}, s10 = {}, s11 = {};
    __builtin_amdgcn_s_setprio(1);
    #pragma unroll
    for (int ks = 0; ks < 4; ++ks)
        s00 = __builtin_amdgcn_mfma_f32_32x32x16_bf16(kA[0][ks], qB[0][ks], s00, 0, 0, 0);
    #pragma unroll
    for (int ks = 0; ks < 4; ++ks)
        s01 = __builtin_amdgcn_mfma_f32_32x32x16_bf16(kA[1][ks], qB[0][ks], s01, 0, 0, 0);
    #pragma unroll
    for (int ks = 0; ks < 4; ++ks)
        s10 = __builtin_amdgcn_mfma_f32_32x32x16_bf16(kA[0][ks], qB[1][ks], s10, 0, 0, 0);
    #pragma unroll
    for (int ks = 0; ks < 4; ++ks)
        s11 = __builtin_amdgcn_mfma_f32_32x32x16_bf16(kA[1][ks], qB[1][ks], s11, 0, 0, 0);
    __builtin_amdgcn_s_setprio(0);

    // ---- V A-frags issued now; latency hides under SM(t0) ----
    bf16x8 vA[2][4];
    #pragma unroll
    for (int eb = 0; eb < 2; ++eb)
        #pragma unroll
        for (int ks = 0; ks < 4; ++ks)
            vA[eb][ks] = *reinterpret_cast<const bf16x8*>(
                vp + (size_t)(eb * 32 + lq) * S_LEN + kv0 + ks * 16 + kcol);

    // ---- SM(t0): VALU chain, overlaps QK(t1)+V-load latency ----
    bf16x8 pB0[4];
    sm_pack<0, MASK>(kv0, qbase, lq, lh, s00, s01, m_acc, l_lane, acc, pB0);

    // ---- PV(t0): issued before SM(t1) -> matrix pipe covers SM1 VALU ----
    __builtin_amdgcn_s_setprio(1);
    #pragma unroll
    for (int eb = 0; eb < 2; ++eb)
        #pragma unroll
        for (int ks = 0; ks < 4; ++ks)
            acc[0][eb] = __builtin_amdgcn_mfma_f32_32x32x16_bf16(
                vA[eb][ks], pB0[ks], acc[0][eb], 0, 0, 0);
    __builtin_amdgcn_s_setprio(0);

    // ---- SM(t1) ----
    bf16x8 pB1[4];
    sm_pack<1, MASK>(kv0, qbase, lq, lh, s10, s11, m_acc, l_lane, acc, pB1);

    // ---- PV(t1) ----
    __builtin_amdgcn_s_setprio(1);
    #pragma unroll
    for (int eb = 0; eb < 2; ++eb)
        #pragma unroll
        for (int ks = 0; ks < 4; ++ks)
            acc[1][eb] = __builtin_amdgcn_mfma_f32_32x32x16_bf16(
                vA[eb][ks], pB1[ks], acc[1][eb], 0, 0, 0);
    __builtin_amdgcn_s_setprio(0);
}

// ---------------------------------------------------------------------------
// Split-K merge helpers (static register indexing only, rule #20).
// LDS region: per wave, lane l owns floats [l*35 .. l*35+33]:
//   [0]=m, [1]=row-sum l, [2..33]=acc (2 eb x 16 regs). Stride 35 ->
//   bank (3l+k)%32: conflict-free.
// ---------------------------------------------------------------------------
template<int T>
__device__ __attribute__((always_inline)) inline void expose_tile(
    float* region, int l, const float (&m_acc)[2], const float (&lt)[2],
    const f32x16 (&acc)[2][2])
{
    float* p = region + l * 35;
    p[0] = m_acc[T];
    p[1] = lt[T];
    #pragma unroll
    for (int eb = 0; eb < 2; ++eb)
        #pragma unroll
        for (int r = 0; r < 16; ++r)
            p[2 + eb * 16 + r] = acc[T][eb][r];
}

template<int T>
__device__ __attribute__((always_inline)) inline void merge_out(
    const float* region, int l, int lh, const float (&m_acc)[2],
    const float (&lt)[2], const f32x16 (&acc)[2][2], float* orow)
{
    const float* p = region + l * 35;
    const float mo = p[0];
    const float lo = p[1];
    const float mn = fmaxf(m_acc[T], mo);
    const float s_own = exp2f(m_acc[T] - mn);
    const float s_oth = exp2f(mo - mn);
    const float liv = 1.0f / (lt[T] * s_own + lo * s_oth);
    #pragma unroll
    for (int eb = 0; eb < 2; ++eb) {
        #pragma unroll
        for (int g = 0; g < 4; ++g) {
            f32x4 ox;
            #pragma unroll
            for (int r = 0; r < 4; ++r) {
                const float oth = p[2 + eb * 16 + g * 4 + r];
                ox[r] = (acc[T][eb][g * 4 + r] * s_own + oth * s_oth) * liv;
            }
            *reinterpret_cast<f32x4*>(orow + eb * 32 + g * 8 + 4 * lh) = ox;
        }
    }
}

// ---------------------------------------------------------------------------
// Causal flash attention, SPLIT-K + T15 pipeline on the LDS-free 32x32 body:
// 2-wave blocks; block owns chunk pair (tp, 31-tp); within a chunk, wave w
// handles kv-blocks of parity w. Merge: wave w exposes tile (1-w), merges +
// writes tile w. 1024 blocks x 2 waves = 8 waves/CU = 2/SIMD.
// (Best verified configuration: R17, 157.27us total / ~89us attn dispatch.
//  Later variants -- per-chunk LPT grid, coalesced LDS staging -- were
//  neutral or worse; reverted.)
// ---------------------------------------------------------------------------
__global__ __launch_bounds__(128, 2) void attn_kernel(
    const __bf16* __restrict__ q, const __bf16* __restrict__ k,
    const __bf16* __restrict__ vt, float* __restrict__ out)
{
    __shared__ float mlds[2 * 64 * 35];   // 17.9 KB

    const int tid = threadIdx.x;
    const int l  = tid & 63;
    const int w  = tid >> 6;             // 0/1: kv parity
    const int lq = l & 31;
    const int lh = l >> 5;
    const int kcol = 8 * lh;

    const int n   = blockIdx.x;          // 0..1023
    const int xcd = n & 7;
    const int m   = n >> 3;              // 0..127
    const int tp  = m >> 3;              // 0..15: chunk pair (tp, 31-tp)
    const int bh  = xcd * 8 + (m & 7);

    const __bf16* __restrict__ kp = k  + (size_t)bh * S_LEN * HDIM;
    const __bf16* __restrict__ vp = vt + (size_t)bh * HDIM * S_LEN;
    const int bq = bh >> 4;
    const int hq = bh & 15;

    #pragma unroll 1
    for (int ph = 0; ph < 2; ++ph) {
        const int qq    = ph ? (31 - tp) : tp;   // 64-row chunk index
        const int qbase = qq * 64;
        const int nkv   = qq + 1;

        // Q B-frags: col = own q-row, k = e (4 slabs of 16)
        const __bf16* __restrict__ qp = q + ((size_t)bh * S_LEN + qbase) * HDIM;
        bf16x8 qB[2][4];
        #pragma unroll
        for (int t = 0; t < 2; ++t)
            #pragma unroll
            for (int ks = 0; ks < 4; ++ks)
                qB[t][ks] = *reinterpret_cast<const bf16x8*>(
                    qp + (size_t)(t * 32 + lq) * HDIM + ks * 16 + kcol);

        float m_acc[2], l_lane[2];
        f32x16 acc[2][2] = {};
        #pragma unroll
        for (int t = 0; t < 2; ++t) { m_acc[t] = -1e30f; l_lane[t] = 0.0f; }

        // ---- split-K: wave w takes kv-block j = w, w+2, ... ----
        #pragma unroll 1
        for (int j = w; j < nkv - 1; j += 2)
            pair_compute<false>(j * 64, qbase, lq, lh, kp, vp,
                                qB, m_acc, l_lane, acc);
        if (((nkv - 1) & 1) == w)
            pair_compute<true>((nkv - 1) * 64, qbase, lq, lh, kp, vp,
                               qB, m_acc, l_lane, acc);

        // ---- wave-local row sums of l (row = lanes l and l^32) ----
        float lt[2];
        lt[0] = l_lane[0] + __shfl_xor(l_lane[0], 32);
        lt[1] = l_lane[1] + __shfl_xor(l_lane[1], 32);

        // ---- expose opposite tile (static indices per arm) ----
        float* myreg = mlds + w * (64 * 35);
        if (w == 0) expose_tile<1>(myreg, l, m_acc, lt, acc);
        else        expose_tile<0>(myreg, l, m_acc, lt, acc);
        __syncthreads();

        // ---- merge + write own tile ----
        const float* other = mlds + (1 - w) * (64 * 35);
        if (w == 0) {
            float* orow = out + (size_t)(bq * S_LEN + qbase + 0 * 32 + lq) * D_DIM + hq * HDIM;
            merge_out<0>(other, l, lh, m_acc, lt, acc, orow);
        } else {
            float* orow = out + (size_t)(bq * S_LEN + qbase + 1 * 32 + lq) * D_DIM + hq * HDIM;
            merge_out<1>(other, l, lh, m_acc, lt, acc, orow);
        }
        __syncthreads();   // LDS reused by next phase
    }
}

extern "C" void kernel_launch(void* const* d_in, const int* in_sizes, int n_in,
                              void* d_out, int out_size, void* d_ws, size_t ws_size,
                              hipStream_t stream)
{
    const float* x  = (const float*)d_in[0];
    const float* Wq = (const float*)d_in[1];
    const float* Wk = (const float*)d_in[2];
    const float* Wv = (const float*)d_in[3];
    float* out = (float*)d_out;

    const size_t x_elems = (size_t)BATCH * S_LEN * D_DIM;
    __bf16* xb   = (__bf16*)d_out;          // scratch in d_out (overwritten)
    __bf16* wcat = xb + x_elems;

    const size_t per_buf = (size_t)BATCH * NHEAD * S_LEN * HDIM;
    __bf16* qb = (__bf16*)d_ws;
    __bf16* kb = qb + per_buf;
    __bf16* vb = kb + per_buf;

    cvt_all_kernel<<<dim3((NX8 + 3 * NW8) / 256), dim3(256), 0, stream>>>(
        x, Wq, Wk, Wv, xb, wcat);

    dim3 grid1(3 * D_DIM / 128, (BATCH * S_LEN) / 128);   // (24, 64)
    proj_gemm_kernel<<<grid1, dim3(256), 0, stream>>>(xb, wcat, qb, kb, vb);

    attn_kernel<<<dim3(1024), dim3(128), 0, stream>>>(qb, kb, vb, out);
}

// Round 22
// 156.010 us; speedup vs baseline: 1.0352x; 1.0031x over previous
//
#include <hip/hip_runtime.h>
#include <hip/hip_bf16.h>

#define BATCH 4
#define S_LEN 2048
#define D_DIM 1024
#define NHEAD 16
#define HDIM 64

// Q pre-scale: 1/sqrt(HDIM) * log2(e), so softmax works in exp2 domain.
#define QSCALE 0.18033688011112042f

typedef __attribute__((ext_vector_type(8))) __bf16 bf16x8;
typedef __attribute__((ext_vector_type(4))) __bf16 bf16x4;
typedef __attribute__((ext_vector_type(4))) float f32x4;
typedef __attribute__((ext_vector_type(16))) float f32x16;

static __device__ inline unsigned int bf16_bits(float f) {
    __bf16 h = (__bf16)f;
    return (unsigned int)__builtin_bit_cast(unsigned short, h);
}
static __device__ inline unsigned int pkbf(float a, float b) {
    return bf16_bits(a) | (bf16_bits(b) << 16);
}

// ---------------------------------------------------------------------------
// Fused fp32 -> bf16 convert for x and the three W matrices (one launch).
// ---------------------------------------------------------------------------
#define NX8 1048576   // x: 8.39M elems / 8
#define NW8 131072    // each W: 1.05M elems / 8 (= 2^17)

__global__ __launch_bounds__(256) void cvt_all_kernel(
    const float* __restrict__ x,  const float* __restrict__ Wq,
    const float* __restrict__ Wk, const float* __restrict__ Wv,
    __bf16* __restrict__ xb, __bf16* __restrict__ wcat)
{
    const int i = blockIdx.x * 256 + threadIdx.x;
    const float* src;
    __bf16* dst;
    if (i < NX8) {
        src = x + (size_t)i * 8;
        dst = xb + (size_t)i * 8;
    } else {
        const int i2 = i - NX8;              // 0 .. 3*NW8-1
        const int w  = i2 >> 17;             // 0..2
        src = ((w == 0) ? Wq : (w == 1) ? Wk : Wv) + (size_t)(i2 & (NW8 - 1)) * 8;
        dst = wcat + (size_t)i2 * 8;
    }
    const f32x4* p = reinterpret_cast<const f32x4*>(src);
    f32x4 a = p[0], b = p[1];
    bf16x8 r;
    r[0] = (__bf16)a[0]; r[1] = (__bf16)a[1]; r[2] = (__bf16)a[2]; r[3] = (__bf16)a[3];
    r[4] = (__bf16)b[0]; r[5] = (__bf16)b[1]; r[6] = (__bf16)b[2]; r[7] = (__bf16)b[3];
    *reinterpret_cast<bf16x8*>(dst) = r;
}

// ---------------------------------------------------------------------------
// Projection GEMM (m97-style): C[m][n] = sum_d xb[m][d] * wb[n][d]
// q output is pre-scaled by QSCALE. q,k -> [bh][s][e]; v -> [bh][e][s].
// ---------------------------------------------------------------------------
__global__ __launch_bounds__(256) void proj_gemm_kernel(
    const __bf16* __restrict__ xb, const __bf16* __restrict__ wb,
    __bf16* __restrict__ qo, __bf16* __restrict__ ko, __bf16* __restrict__ vto)
{
    __shared__ __bf16 As[128][32];
    __shared__ __bf16 Bs[128][32];

    const int tid = threadIdx.x;
    const int l  = tid & 63;
    const int w  = tid >> 6;
    const int wm = w >> 1, wn = w & 1;
    const int lr = l & 15, lg = l >> 4, lk = lg * 8;
    const int m0 = blockIdx.y * 128;
    const int n0 = blockIdx.x * 128;
    const int mat = n0 >> 10;           // 0=q,1=k,2=v
    const int nb  = n0 & 1023;

    const int sr = l >> 2;
    const int sc = (l & 3) * 8;
    const int g0 = w * 2;

    f32x4 acc[4][4] = {};

    for (int d = 0; d < D_DIM; d += 32) {
        __builtin_amdgcn_global_load_lds(
            (const __attribute__((address_space(1))) void*)(xb + (size_t)(m0 + g0 * 16 + sr) * D_DIM + d + sc),
            (__attribute__((address_space(3))) void*)(&As[g0 * 16][0]), 16, 0, 0);
        __builtin_amdgcn_global_load_lds(
            (const __attribute__((address_space(1))) void*)(xb + (size_t)(m0 + (g0 + 1) * 16 + sr) * D_DIM + d + sc),
            (__attribute__((address_space(3))) void*)(&As[(g0 + 1) * 16][0]), 16, 0, 0);
        __builtin_amdgcn_global_load_lds(
            (const __attribute__((address_space(1))) void*)(wb + (size_t)(n0 + g0 * 16 + sr) * D_DIM + d + sc),
            (__attribute__((address_space(3))) void*)(&Bs[g0 * 16][0]), 16, 0, 0);
        __builtin_amdgcn_global_load_lds(
            (const __attribute__((address_space(1))) void*)(wb + (size_t)(n0 + (g0 + 1) * 16 + sr) * D_DIM + d + sc),
            (__attribute__((address_space(3))) void*)(&Bs[(g0 + 1) * 16][0]), 16, 0, 0);
        __syncthreads();

        bf16x8 af[4], bfr[4];
        #pragma unroll
        for (int mi = 0; mi < 4; ++mi)
            af[mi] = *reinterpret_cast<const bf16x8*>(&As[wm * 64 + mi * 16 + lr][lk]);
        #pragma unroll
        for (int ni = 0; ni < 4; ++ni)
            bfr[ni] = *reinterpret_cast<const bf16x8*>(&Bs[wn * 64 + ni * 16 + lr][lk]);
        #pragma unroll
        for (int mi = 0; mi < 4; ++mi) {
            #pragma unroll
            for (int ni = 0; ni < 4; ++ni)
                acc[mi][ni] = __builtin_amdgcn_mfma_f32_16x16x32_bf16(
                    af[mi], bfr[ni], acc[mi][ni], 0, 0, 0);
        }
        __syncthreads();
    }

    const float oscale = (mat == 0) ? QSCALE : 1.0f;
    #pragma unroll
    for (int mi = 0; mi < 4; ++mi) {
        const int mrow = m0 + wm * 64 + mi * 16 + lg * 4;
        const int b = mrow >> 11;
        const int s = mrow & (S_LEN - 1);
        #pragma unroll
        for (int ni = 0; ni < 4; ++ni) {
            const int n = nb + wn * 64 + ni * 16 + lr;
            const int h = n >> 6;
            const int e = n & 63;
            if (mat == 2) {
                bf16x4 pk;
                #pragma unroll
                for (int r = 0; r < 4; ++r) pk[r] = (__bf16)acc[mi][ni][r];
                *reinterpret_cast<bf16x4*>(
                    vto + ((size_t)(b * NHEAD + h) * HDIM + e) * S_LEN + s) = pk;
            } else {
                __bf16* __restrict__ dst = (mat == 0) ? qo : ko;
                #pragma unroll
                for (int r = 0; r < 4; ++r)
                    dst[((size_t)(b * NHEAD + h) * S_LEN + (s + r)) * HDIM + e] =
                        (__bf16)(acc[mi][ni][r] * oscale);
            }
        }
    }
}

// ---------------------------------------------------------------------------
// Softmax + pack for one 32-row tile T (static index). Consumes s0/s1
// (scores for kv blocks 0/1), updates m/l/acc[T], emits 4 PV B-frags.
// psum uses an explicit 5-level TREE reduction (the flat += chain was a
// strict-FP 32-add serial dependency ~190cy on the critical path).
// ---------------------------------------------------------------------------
template<int T, bool MASK>
__device__ __attribute__((always_inline)) inline void sm_pack(
    int kv0, int qbase, int lq, int lh,
    f32x16& s0, f32x16& s1,
    float (&m_acc)[2], float (&l_lane)[2], f32x16 (&acc)[2][2],
    bf16x8 (&pB)[4])
{
    if (MASK) {
        const int qrow = qbase + T * 32 + lq;
        #pragma unroll
        for (int r = 0; r < 16; ++r) {
            const int kvl = (r & 3) + 8 * (r >> 2) + 4 * lh;
            if (kv0 + kvl > qrow)      s0[r] = -1e30f;
            if (kv0 + 32 + kvl > qrow) s1[r] = -1e30f;
        }
    }

    float tm[8];
    #pragma unroll
    for (int r = 0; r < 8; ++r)
        tm[r] = fmaxf(fmaxf(s0[r], s0[r + 8]), fmaxf(s1[r], s1[r + 8]));
    float mx = fmaxf(fmaxf(fmaxf(tm[0], tm[1]), fmaxf(tm[2], tm[3])),
                     fmaxf(fmaxf(tm[4], tm[5]), fmaxf(tm[6], tm[7])));

    if (!__all(mx - m_acc[T] <= 8.0f)) {
        mx = fmaxf(mx, __shfl_xor(mx, 32));
        const float mnew = fmaxf(m_acc[T], mx);
        const float sc = exp2f(m_acc[T] - mnew);
        l_lane[T] *= sc;
        acc[T][0] *= sc;
        acc[T][1] *= sc;
        m_acc[T] = mnew;
    }

    const float mt = m_acc[T];
    float p0[16], p1[16];
    #pragma unroll
    for (int r = 0; r < 16; ++r) p0[r] = exp2f(s0[r] - mt);
    #pragma unroll
    for (int r = 0; r < 16; ++r) p1[r] = exp2f(s1[r] - mt);

    // ---- tree-reduced psum: 5 levels (~30cy) vs 32-chain (~190cy) ----
    float t16[16];
    #pragma unroll
    for (int r = 0; r < 16; ++r) t16[r] = p0[r] + p1[r];
    float t8[8];
    #pragma unroll
    for (int r = 0; r < 8; ++r) t8[r] = t16[r] + t16[r + 8];
    float t4[4];
    #pragma unroll
    for (int r = 0; r < 4; ++r) t4[r] = t8[r] + t8[r + 4];
    l_lane[T] += (t4[0] + t4[1]) + (t4[2] + t4[3]);

    #pragma unroll
    for (int sl = 0; sl < 2; ++sl) {
        const int b = sl * 8;
        {
            unsigned A = pkbf(p0[b + 0], p0[b + 1]);
            unsigned C = pkbf(p0[b + 2], p0[b + 3]);
            unsigned B = pkbf(p0[b + 4], p0[b + 5]);
            unsigned D = pkbf(p0[b + 6], p0[b + 7]);
            auto r0 = __builtin_amdgcn_permlane32_swap((int)A, (int)B, false, false);
            auto r1 = __builtin_amdgcn_permlane32_swap((int)C, (int)D, false, false);
            uint4 u;
            u.x = (unsigned)r0[0]; u.y = (unsigned)r1[0];
            u.z = (unsigned)r0[1]; u.w = (unsigned)r1[1];
            pB[sl] = __builtin_bit_cast(bf16x8, u);
        }
        {
            unsigned A = pkbf(p1[b + 0], p1[b + 1]);
            unsigned C = pkbf(p1[b + 2], p1[b + 3]);
            unsigned B = pkbf(p1[b + 4], p1[b + 5]);
            unsigned D = pkbf(p1[b + 6], p1[b + 7]);
            auto r0 = __builtin_amdgcn_permlane32_swap((int)A, (int)B, false, false);
            auto r1 = __builtin_amdgcn_permlane32_swap((int)C, (int)D, false, false);
            uint4 u;
            u.x = (unsigned)r0[0]; u.y = (unsigned)r1[0];
            u.z = (unsigned)r0[1]; u.w = (unsigned)r1[1];
            pB[2 + sl] = __builtin_bit_cast(bf16x8, u);
        }
    }
}

// ---------------------------------------------------------------------------
// 32x32 MFMA attention iteration, LDS-free, T15 double-pipeline:
// QK both tiles issued up front (SM(t0) VALU hides under QK(t1) MFMA exec);
// V loads issued before SM0 (L2 latency hidden under softmax);
// PV(t0) MFMAs issued BEFORE SM(t1) (PV0 matrix-pipe exec hides SM1 VALU).
// ---------------------------------------------------------------------------
template<bool MASK>
__device__ __attribute__((always_inline)) inline void pair_compute(
    int kv0, int qbase, int lq, int lh,
    const __bf16* __restrict__ kp, const __bf16* __restrict__ vp,
    const bf16x8 (&qB)[2][4],
    float (&m_acc)[2], float (&l_lane)[2], f32x16 (&acc)[2][2])
{
    const int kcol = 8 * lh;

    // ---- K A-frags (shared by both q-tiles) ----
    bf16x8 kA[2][4];
    #pragma unroll
    for (int kvb = 0; kvb < 2; ++kvb)
        #pragma unroll
        for (int ks = 0; ks < 4; ++ks)
            kA[kvb][ks] = *reinterpret_cast<const bf16x8*>(
                kp + (size_t)(kv0 + kvb * 32 + lq) * HDIM + ks * 16 + kcol);

    // ---- QK^T both tiles, issued back-to-back ----
    f32x16 s00 = {}, s01 = {}, s10 = {}, s11 = {};
    __builtin_amdgcn_s_setprio(1);
    #pragma unroll
    for (int ks = 0; ks < 4; ++ks)
        s00 = __builtin_amdgcn_mfma_f32_32x32x16_bf16(kA[0][ks], qB[0][ks], s00, 0, 0, 0);
    #pragma unroll
    for (int ks = 0; ks < 4; ++ks)
        s01 = __builtin_amdgcn_mfma_f32_32x32x16_bf16(kA[1][ks], qB[0][ks], s01, 0, 0, 0);
    #pragma unroll
    for (int ks = 0; ks < 4; ++ks)
        s10 = __builtin_amdgcn_mfma_f32_32x32x16_bf16(kA[0][ks], qB[1][ks], s10, 0, 0, 0);
    #pragma unroll
    for (int ks = 0; ks < 4; ++ks)
        s11 = __builtin_amdgcn_mfma_f32_32x32x16_bf16(kA[1][ks], qB[1][ks], s11, 0, 0, 0);
    __builtin_amdgcn_s_setprio(0);

    // ---- V A-frags issued now; latency hides under SM(t0) ----
    bf16x8 vA[2][4];
    #pragma unroll
    for (int eb = 0; eb < 2; ++eb)
        #pragma unroll
        for (int ks = 0; ks < 4; ++ks)
            vA[eb][ks] = *reinterpret_cast<const bf16x8*>(
                vp + (size_t)(eb * 32 + lq) * S_LEN + kv0 + ks * 16 + kcol);

    // ---- SM(t0): VALU chain, overlaps QK(t1)+V-load latency ----
    bf16x8 pB0[4];
    sm_pack<0, MASK>(kv0, qbase, lq, lh, s00, s01, m_acc, l_lane, acc, pB0);

    // ---- PV(t0): issued before SM(t1) -> matrix pipe covers SM1 VALU ----
    __builtin_amdgcn_s_setprio(1);
    #pragma unroll
    for (int eb = 0; eb < 2; ++eb)
        #pragma unroll
        for (int ks = 0; ks < 4; ++ks)
            acc[0][eb] = __builtin_amdgcn_mfma_f32_32x32x16_bf16(
                vA[eb][ks], pB0[ks], acc[0][eb], 0, 0, 0);
    __builtin_amdgcn_s_setprio(0);

    // ---- SM(t1) ----
    bf16x8 pB1[4];
    sm_pack<1, MASK>(kv0, qbase, lq, lh, s10, s11, m_acc, l_lane, acc, pB1);

    // ---- PV(t1) ----
    __builtin_amdgcn_s_setprio(1);
    #pragma unroll
    for (int eb = 0; eb < 2; ++eb)
        #pragma unroll
        for (int ks = 0; ks < 4; ++ks)
            acc[1][eb] = __builtin_amdgcn_mfma_f32_32x32x16_bf16(
                vA[eb][ks], pB1[ks], acc[1][eb], 0, 0, 0);
    __builtin_amdgcn_s_setprio(0);
}

// ---------------------------------------------------------------------------
// Split-K merge helpers (static register indexing only, rule #20).
// LDS region: per wave, lane l owns floats [l*35 .. l*35+33]:
//   [0]=m, [1]=row-sum l, [2..33]=acc (2 eb x 16 regs). Stride 35 ->
//   bank (3l+k)%32: conflict-free.
// ---------------------------------------------------------------------------
template<int T>
__device__ __attribute__((always_inline)) inline void expose_tile(
    float* region, int l, const float (&m_acc)[2], const float (&lt)[2],
    const f32x16 (&acc)[2][2])
{
    float* p = region + l * 35;
    p[0] = m_acc[T];
    p[1] = lt[T];
    #pragma unroll
    for (int eb = 0; eb < 2; ++eb)
        #pragma unroll
        for (int r = 0; r < 16; ++r)
            p[2 + eb * 16 + r] = acc[T][eb][r];
}

template<int T>
__device__ __attribute__((always_inline)) inline void merge_out(
    const float* region, int l, int lh, const float (&m_acc)[2],
    const float (&lt)[2], const f32x16 (&acc)[2][2], float* orow)
{
    const float* p = region + l * 35;
    const float mo = p[0];
    const float lo = p[1];
    const float mn = fmaxf(m_acc[T], mo);
    const float s_own = exp2f(m_acc[T] - mn);
    const float s_oth = exp2f(mo - mn);
    const float liv = 1.0f / (lt[T] * s_own + lo * s_oth);
    #pragma unroll
    for (int eb = 0; eb < 2; ++eb) {
        #pragma unroll
        for (int g = 0; g < 4; ++g) {
            f32x4 ox;
            #pragma unroll
            for (int r = 0; r < 4; ++r) {
                const float oth = p[2 + eb * 16 + g * 4 + r];
                ox[r] = (acc[T][eb][g * 4 + r] * s_own + oth * s_oth) * liv;
            }
            *reinterpret_cast<f32x4*>(orow + eb * 32 + g * 8 + 4 * lh) = ox;
        }
    }
}

// ---------------------------------------------------------------------------
// Causal flash attention, SPLIT-K + T15 pipeline on the LDS-free 32x32 body:
// 2-wave blocks; block owns chunk pair (tp, 31-tp); within a chunk, wave w
// handles kv-blocks of parity w. Merge: wave w exposes tile (1-w), merges +
// writes tile w. 1024 blocks x 2 waves = 8 waves/CU = 2/SIMD.
// ---------------------------------------------------------------------------
__global__ __launch_bounds__(128, 2) void attn_kernel(
    const __bf16* __restrict__ q, const __bf16* __restrict__ k,
    const __bf16* __restrict__ vt, float* __restrict__ out)
{
    __shared__ float mlds[2 * 64 * 35];   // 17.9 KB

    const int tid = threadIdx.x;
    const int l  = tid & 63;
    const int w  = tid >> 6;             // 0/1: kv parity
    const int lq = l & 31;
    const int lh = l >> 5;
    const int kcol = 8 * lh;

    const int n   = blockIdx.x;          // 0..1023
    const int xcd = n & 7;
    const int m   = n >> 3;              // 0..127
    const int tp  = m >> 3;              // 0..15: chunk pair (tp, 31-tp)
    const int bh  = xcd * 8 + (m & 7);

    const __bf16* __restrict__ kp = k  + (size_t)bh * S_LEN * HDIM;
    const __bf16* __restrict__ vp = vt + (size_t)bh * HDIM * S_LEN;
    const int bq = bh >> 4;
    const int hq = bh & 15;

    #pragma unroll 1
    for (int ph = 0; ph < 2; ++ph) {
        const int qq    = ph ? (31 - tp) : tp;   // 64-row chunk index
        const int qbase = qq * 64;
        const int nkv   = qq + 1;

        // Q B-frags: col = own q-row, k = e (4 slabs of 16)
        const __bf16* __restrict__ qp = q + ((size_t)bh * S_LEN + qbase) * HDIM;
        bf16x8 qB[2][4];
        #pragma unroll
        for (int t = 0; t < 2; ++t)
            #pragma unroll
            for (int ks = 0; ks < 4; ++ks)
                qB[t][ks] = *reinterpret_cast<const bf16x8*>(
                    qp + (size_t)(t * 32 + lq) * HDIM + ks * 16 + kcol);

        float m_acc[2], l_lane[2];
        f32x16 acc[2][2] = {};
        #pragma unroll
        for (int t = 0; t < 2; ++t) { m_acc[t] = -1e30f; l_lane[t] = 0.0f; }

        // ---- split-K: wave w takes kv-block j = w, w+2, ... ----
        #pragma unroll 1
        for (int j = w; j < nkv - 1; j += 2)
            pair_compute<false>(j * 64, qbase, lq, lh, kp, vp,
                                qB, m_acc, l_lane, acc);
        if (((nkv - 1) & 1) == w)
            pair_compute<true>((nkv - 1) * 64, qbase, lq, lh, kp, vp,
                               qB, m_acc, l_lane, acc);

        // ---- wave-local row sums of l (row = lanes l and l^32) ----
        float lt[2];
        lt[0] = l_lane[0] + __shfl_xor(l_lane[0], 32);
        lt[1] = l_lane[1] + __shfl_xor(l_lane[1], 32);

        // ---- expose opposite tile (static indices per arm) ----
        float* myreg = mlds + w * (64 * 35);
        if (w == 0) expose_tile<1>(myreg, l, m_acc, lt, acc);
        else        expose_tile<0>(myreg, l, m_acc, lt, acc);
        __syncthreads();

        // ---- merge + write own tile ----
        const float* other = mlds + (1 - w) * (64 * 35);
        if (w == 0) {
            float* orow = out + (size_t)(bq * S_LEN + qbase + 0 * 32 + lq) * D_DIM + hq * HDIM;
            merge_out<0>(other, l, lh, m_acc, lt, acc, orow);
        } else {
            float* orow = out + (size_t)(bq * S_LEN + qbase + 1 * 32 + lq) * D_DIM + hq * HDIM;
            merge_out<1>(other, l, lh, m_acc, lt, acc, orow);
        }
        __syncthreads();   // LDS reused by next phase
    }
}

extern "C" void kernel_launch(void* const* d_in, const int* in_sizes, int n_in,
                              void* d_out, int out_size, void* d_ws, size_t ws_size,
                              hipStream_t stream)
{
    const float* x  = (const float*)d_in[0];
    const float* Wq = (const float*)d_in[1];
    const float* Wk = (const float*)d_in[2];
    const float* Wv = (const float*)d_in[3];
    float* out = (float*)d_out;

    const size_t x_elems = (size_t)BATCH * S_LEN * D_DIM;
    __bf16* xb   = (__bf16*)d_out;          // scratch in d_out (overwritten)
    __bf16* wcat = xb + x_elems;

    const size_t per_buf = (size_t)BATCH * NHEAD * S_LEN * HDIM;
    __bf16* qb = (__bf16*)d_ws;
    __bf16* kb = qb + per_buf;
    __bf16* vb = kb + per_buf;

    cvt_all_kernel<<<dim3((NX8 + 3 * NW8) / 256), dim3(256), 0, stream>>>(
        x, Wq, Wk, Wv, xb, wcat);

    dim3 grid1(3 * D_DIM / 128, (BATCH * S_LEN) / 128);   // (24, 64)
    proj_gemm_kernel<<<grid1, dim3(256), 0, stream>>>(xb, wcat, qb, kb, vb);

    attn_kernel<<<dim3(1024), dim3(128), 0, stream>>>(qb, kb, vb, out);
}